// Round 1
// baseline (55931.628 us; speedup 1.0000x reference)
//
#include <hip/hip_runtime.h>

// SCLSTM, MI355X persistent-grid implementation.
//
// Numerical dead-code: s0 == 0 and s is only ever multiplied (s = s*r), so
// s == 0 forever, st output == 0, and slot_info == tanh(sb[l]) (constant).
// W_ir/b_ir/W_hr/b_hr/sW never influence any output. Remaining compute is a
// 2-layer LSTM with constant additive tanh(sb) in the cell update.

constexpr int NBLK = 256;   // persistent blocks (<= 256 CUs -> co-resident, barrier-safe)
constexpr int NTHR = 512;   // 8 waves
constexpr int Bsz = 64, Tt = 512, INsz = 512, Hsz = 512, Lsz = 2;

constexpr long long OUT_HT = (long long)Bsz * Tt * Hsz;          // outputs: 16,777,216 floats
constexpr long long OUT_CT = OUT_HT + (long long)Bsz * Lsz * Hsz; // ht: +65,536
constexpr long long OUT_ST = OUT_CT + (long long)Bsz * Lsz * Hsz; // ct: +65,536 ; st: +8,192
constexpr int HBUFN = Bsz * Lsz * Hsz;                            // 65,536 floats per h ping-pong buffer

// ws layout (floats): [0]=barrier count, [1]=barrier generation, [64..] h ping-pong x2
__global__ __launch_bounds__(256) void sclstm_init(float* __restrict__ ws,
                                                   float* __restrict__ out) {
    int idx = blockIdx.x * blockDim.x + threadIdx.x;
    int str = gridDim.x * blockDim.x;
    for (int i = idx; i < 64 + 2 * HBUFN; i += str) ws[i] = 0.f;          // barrier vars + h buffers
    for (int i = idx; i < Bsz * Lsz * Hsz + Bsz * 128; i += str)          // ct state + st (stays 0)
        out[OUT_CT + i] = 0.f;
}

__device__ __forceinline__ float sigm(float x) { return 1.f / (1.f + __expf(-x)); }
__device__ __forceinline__ float ftanh(float x) {
    float e = __expf(2.f * x);            // inf-safe: saturates to +-1
    return 1.f - 2.f / (e + 1.f);
}

__device__ __forceinline__ void grid_barrier(unsigned* cnt, unsigned* gen) {
    __syncthreads();
    if (threadIdx.x == 0) {
        __threadfence();  // make this block's global writes agent-visible
        unsigned g = __hip_atomic_load(gen, __ATOMIC_RELAXED, __HIP_MEMORY_SCOPE_AGENT);
        unsigned a = __hip_atomic_fetch_add(cnt, 1u, __ATOMIC_ACQ_REL, __HIP_MEMORY_SCOPE_AGENT);
        if (a == (unsigned)(NBLK - 1)) {
            __hip_atomic_store(cnt, 0u, __ATOMIC_RELAXED, __HIP_MEMORY_SCOPE_AGENT);
            __hip_atomic_store(gen, g + 1u, __ATOMIC_RELEASE, __HIP_MEMORY_SCOPE_AGENT);
        } else {
            while (__hip_atomic_load(gen, __ATOMIC_ACQUIRE, __HIP_MEMORY_SCOPE_AGENT) == g) {
                __builtin_amdgcn_s_sleep(8);
            }
        }
    }
    __syncthreads();
}

// Block tile: 8 h-features (m0..m0+7 -> 32 gate rows) x 16 batch (b0..b0+15).
// 64 feature-groups x 4 batch-groups = 256 blocks.
// Wave mapping: wave owns 4 gate rows; lane = b_rel*4 + ks (16 batch x 4-way K split).
__global__ __launch_bounds__(NTHR) void sclstm_main(
    const float* __restrict__ inputs,   // (B,T,IN)
    const float* __restrict__ gW,       // (L, 2048, 1024)
    const float* __restrict__ gb,       // (L, 2048)
    const float* __restrict__ sbias,    // (L, 512)
    float* __restrict__ out,
    float* __restrict__ ws)
{
    __shared__ float in_lds[16][516];   // 16 batch x 512 K-panel, +4 pad (2-way conflicts only)
    __shared__ float gbuf[32][17];      // gate dot results [local_row][b_rel]

    unsigned* cnt = (unsigned*)ws;
    unsigned* gen = cnt + 1;
    float* hbuf0 = ws + 64;
    float* hbuf1 = hbuf0 + HBUFN;

    const int tid = threadIdx.x;
    const int m0 = (blockIdx.x & 63) * 8;
    const int b0 = (blockIdx.x >> 6) * 16;
    const int wave = tid >> 6;
    const int lane = tid & 63;
    const int b_rel = lane >> 2;
    const int ks = lane & 3;
    const int koff = ks * 4;
    const int stg_b = tid >> 7;          // staging: 4 batch rows per iteration
    const int stg_k = (tid & 127) * 4;   // staging: float4 column

    for (int t = 0; t < Tt; ++t) {
        float* hprev = (t & 1) ? hbuf1 : hbuf0;
        float* hnext = (t & 1) ? hbuf0 : hbuf1;
        for (int l = 0; l < Lsz; ++l) {
            float acc0 = 0.f, acc1 = 0.f, acc2 = 0.f, acc3 = 0.f;
            const float* rp0;
            const float* rp1;
            const float* rp2;
            const float* rp3;
            {
                const float* wbase = gW + (long long)l * 2048 * 1024;
                int lr = wave * 4;  // local rows lr..lr+3 ; gate g = lr>>3, feat mi = lr&7
                rp0 = wbase + (long long)(((lr + 0) >> 3) * 512 + m0 + ((lr + 0) & 7)) * 1024;
                rp1 = wbase + (long long)(((lr + 1) >> 3) * 512 + m0 + ((lr + 1) & 7)) * 1024;
                rp2 = wbase + (long long)(((lr + 2) >> 3) * 512 + m0 + ((lr + 2) & 7)) * 1024;
                rp3 = wbase + (long long)(((lr + 3) >> 3) * 512 + m0 + ((lr + 3) & 7)) * 1024;
            }
            #pragma unroll
            for (int pass = 0; pass < 2; ++pass) {
                if (pass) __syncthreads();  // previous K-panel fully consumed
                // stage K-panel: pass0 = cur (x_t or h0_new), pass1 = h_l (prev step)
                #pragma unroll
                for (int it = 0; it < 4; ++it) {
                    int bb = it * 4 + stg_b;
                    const float* src;
                    if (pass == 0) {
                        src = (l == 0)
                            ? inputs + ((long long)(b0 + bb) * Tt + t) * INsz + stg_k
                            : hnext + (b0 + bb) * (Lsz * Hsz) + stg_k;          // h0 of this step
                    } else {
                        src = hprev + (b0 + bb) * (Lsz * Hsz) + l * Hsz + stg_k; // h_l of prev step
                    }
                    *(float4*)&in_lds[bb][stg_k] = *(const float4*)src;
                }
                __syncthreads();
                const int po = pass * 512;
                #pragma unroll 4
                for (int i = 0; i < 32; ++i) {
                    const int o = i * 16 + koff;
                    float4 v  = *(const float4*)&in_lds[b_rel][o];
                    float4 w0 = *(const float4*)(rp0 + po + o);
                    float4 w1 = *(const float4*)(rp1 + po + o);
                    float4 w2 = *(const float4*)(rp2 + po + o);
                    float4 w3 = *(const float4*)(rp3 + po + o);
                    acc0 = fmaf(w0.x, v.x, fmaf(w0.y, v.y, fmaf(w0.z, v.z, fmaf(w0.w, v.w, acc0))));
                    acc1 = fmaf(w1.x, v.x, fmaf(w1.y, v.y, fmaf(w1.z, v.z, fmaf(w1.w, v.w, acc1))));
                    acc2 = fmaf(w2.x, v.x, fmaf(w2.y, v.y, fmaf(w2.z, v.z, fmaf(w2.w, v.w, acc2))));
                    acc3 = fmaf(w3.x, v.x, fmaf(w3.y, v.y, fmaf(w3.z, v.z, fmaf(w3.w, v.w, acc3))));
                }
            }
            // reduce 4-way K split (lanes b_rel*4 + {0..3})
            float accs[4] = {acc0, acc1, acc2, acc3};
            #pragma unroll
            for (int j = 0; j < 4; ++j) {
                float a = accs[j];
                a += __shfl_xor(a, 1);
                a += __shfl_xor(a, 2);
                if (ks == 0) gbuf[wave * 4 + j][b_rel] = a;
            }
            __syncthreads();
            // elementwise LSTM update for the block's 8 features x 16 batch
            if (tid < 128) {
                int mi = tid & 7, bb = tid >> 3;
                int m = m0 + mi;
                const float* gbl = gb + l * 2048;
                float ig = gbuf[0 + mi][bb]  + gbl[m];
                float fg = gbuf[8 + mi][bb]  + gbl[512 + m];
                float og = gbuf[16 + mi][bb] + gbl[1024 + m];
                float nf = gbuf[24 + mi][bb] + gbl[1536 + m];
                float slotc = ftanh(sbias[l * Hsz + m]);   // tanh(sb): s==0 always
                long long cidx = OUT_CT + (long long)(b0 + bb) * (Lsz * Hsz) + l * Hsz + m;
                float cn = sigm(fg) * out[cidx] + sigm(ig) * ftanh(nf) + slotc;
                float hn = sigm(og) * ftanh(cn);
                out[cidx] = cn;                                             // c state in-place (owner-only)
                hnext[(b0 + bb) * (Lsz * Hsz) + l * Hsz + m] = hn;
                if (l == 1)
                    out[((long long)(b0 + bb) * Tt + t) * Hsz + m] = hn;    // outputs[b][t][:]
                if (t == Tt - 1)
                    out[OUT_HT + (long long)(b0 + bb) * (Lsz * Hsz) + l * Hsz + m] = hn;  // ht
            }
            grid_barrier(cnt, gen);
        }
    }
}

extern "C" void kernel_launch(void* const* d_in, const int* in_sizes, int n_in,
                              void* d_out, int out_size, void* d_ws, size_t ws_size,
                              hipStream_t stream) {
    (void)in_sizes; (void)n_in; (void)out_size; (void)ws_size;
    const float* inputs = (const float*)d_in[0];
    // d_in[1..4] = W_ir, b_ir, W_hr, b_hr : numerically dead (s == 0 forever)
    const float* gW = (const float*)d_in[5];
    const float* gb = (const float*)d_in[6];
    // d_in[7] = sW : dead (s == 0)
    const float* sbias = (const float*)d_in[8];
    float* out = (float*)d_out;
    float* ws = (float*)d_ws;

    hipLaunchKernelGGL(sclstm_init, dim3(256), dim3(256), 0, stream, ws, out);
    hipLaunchKernelGGL(sclstm_main, dim3(NBLK), dim3(NTHR), 0, stream,
                       inputs, gW, gb, sbias, out, ws);
}

// Round 2
// 9766.991 us; speedup vs baseline: 5.7266x; 5.7266x over previous
//
#include <hip/hip_runtime.h>

// SCLSTM on MI355X — persistent grid, weights-in-registers, group barriers.
//
// Dead code (verified passing in R1): s==0 forever => st==0, slot_info==tanh(sb[l]),
// W_ir/b_ir/W_hr/b_hr/sW never affect outputs. Remaining: 2-layer LSTM, B=64,T=512,H=512.
//
// Decomposition: 256 blocks x 512 thr. Block = (8 features x 16 batch), both layers.
//   4 independent sync-groups of 64 blocks (group = batch tile; no cross-group data flow).
//   Lane (r = tid&31 : 32 gate-rows, s = tid>>5 : 16 K-slices of 32 floats).
//   Weights in VGPRs: 2 layers x 2 K-passes x 8 float4 = 128 VGPRs/lane (loaded once).
// Sync protocol: all cross-block h traffic via agent-scope atomics (sc1 -> LIC-coherent),
//   so NO per-phase L2 writeback/invalidate fences; barrier = per-block slot store +
//   wave-0 poll of 64 slots (1 per lane, divergent-loop convergence).

constexpr int NBLK = 256, NTHR = 512;
constexpr int Bsz = 64, Tt = 512, INsz = 512, Hsz = 512, Lsz = 2;

constexpr long long OUT_HT = (long long)Bsz * Tt * Hsz;            // outputs
constexpr long long OUT_CT = OUT_HT + (long long)Bsz * Lsz * Hsz;  // ht
constexpr long long OUT_ST = OUT_CT + (long long)Bsz * Lsz * Hsz;  // ct ; st after
constexpr int SLOTN = 4 * 64 * 16;            // ints: 4 groups x 64 slots x 64B padding
constexpr int HBUFN = Bsz * Lsz * Hsz;        // floats per h ping-pong buffer

template<int N> struct IC { static constexpr int value = N; };

__global__ __launch_bounds__(256) void sclstm_init(float* __restrict__ ws,
                                                   float* __restrict__ out) {
    int i = blockIdx.x * blockDim.x + threadIdx.x, st = gridDim.x * blockDim.x;
    for (int k = i; k < SLOTN + 2 * HBUFN; k += st) ws[k] = 0.f;  // slots + h buffers
    for (int k = i; k < Bsz * 128; k += st) out[OUT_ST + k] = 0.f; // st == 0 always
}

__device__ __forceinline__ float sigm(float x) { return 1.f / (1.f + __expf(-x)); }
__device__ __forceinline__ float ftanh(float x) {
    float e = __expf(2.f * x);
    return 1.f - 2.f / (e + 1.f);
}

// Stage 1KB: 64 lanes x 16B. gbase/lbase wave-uniform; builtin scatters lane i at lbase+16i.
__device__ __forceinline__ void stage16(const float* gbase, float* lbase) {
    int lane = threadIdx.x & 63;
#if __has_builtin(__builtin_amdgcn_global_load_lds)
    __builtin_amdgcn_global_load_lds(
        (const __attribute__((address_space(1))) void*)(gbase + lane * 4),
        (__attribute__((address_space(3))) void*)lbase, 16, 0, 0);
#else
    *(float4*)(lbase + lane * 4) = *(const float4*)(gbase + lane * 4);
#endif
}

__global__ __launch_bounds__(NTHR, 2) void sclstm_main(
    const float* __restrict__ inputs,   // (B,T,IN)
    const float* __restrict__ gW,       // (L, 2048, 1024)
    const float* __restrict__ gb,       // (L, 2048)
    const float* __restrict__ sbias,    // (L, 512)
    float* __restrict__ out,
    float* __restrict__ ws)
{
    __shared__ float in_lds[16 * 512];      // 16 batch x K-512 panel          (32 KB)
    __shared__ float part_lds[16 * 8 * 32]; // [b][wavepair][r] partial sums   (16 KB)
    __shared__ float gate_lds[32 * 17];     // [r][b] gate values              (2.2 KB)

    int* slots = (int*)ws;
    float* hbuf0 = ws + SLOTN;
    float* hbuf1 = hbuf0 + HBUFN;

    const int tid = threadIdx.x;
    const int blk = blockIdx.x;
    const int grp = blk & 3;                // batch-tile group (independent sync domain)
    const int myidx = blk >> 2;             // 0..63 within group
    const int slotbase = grp * 64 * 16;
    const int b0 = grp * 16;
    const int m0 = (blk >> 2) * 8;          // feature tile
    const int r = tid & 31;                 // gate-row: gate g=r>>3, feature mi=r&7
    const int s = tid >> 5;                 // K-slice 0..15 (32 floats each)
    const int wave = tid >> 6;

    const int grow = (r >> 3) * 512 + m0 + (r & 7);   // global gate row

    // ---- one-time preloads -------------------------------------------------
    float4 wv[2][2][8];                     // [layer][pass][j] -> 128 VGPRs
    #pragma unroll
    for (int l = 0; l < 2; ++l)
        #pragma unroll
        for (int p = 0; p < 2; ++p)
            #pragma unroll
            for (int j = 0; j < 8; ++j)
                wv[l][p][j] = *(const float4*)(gW + (((size_t)l * 2048 + grow) * 1024)
                                               + p * 512 + s * 32 + j * 4);
    float gbias[2] = { gb[grow], gb[2048 + grow] };
    float slotc[2] = { 0.f, 0.f };
    if (tid < 128)
        for (int l = 0; l < 2; ++l)
            slotc[l] = ftanh(sbias[l * 512 + m0 + (tid & 7)]);
    float c0 = 0.f, c1 = 0.f;               // cell state (tid<128: feature tid&7, batch tid>>3)

    auto phase = [&](auto Lc, int t, const float* hprev, float* hnext, int ph) {
        constexpr int L = decltype(Lc)::value;
        #pragma unroll
        for (int p = 0; p < 2; ++p) {
            // ---- stage K-panel (16 batch x 512) into in_lds ----
            if (L == 0 && p == 0) {
                // x(t): constant input, normal cached path, async DMA
                #pragma unroll
                for (int q = 0; q < 4; ++q) {
                    int chunk = wave * 4 + q, b = chunk >> 1, half = chunk & 1;
                    stage16(inputs + ((size_t)(b0 + b) * Tt + t) * INsz + half * 256,
                            &in_lds[chunk * 256]);
                }
            } else {
                // h data from other blocks: agent-scope atomic loads (LIC-coherent)
                const float* hsrc = (p == 1) ? hprev : hnext;
                const int hoff = (p == 1) ? L * 512 : 0;
                float v[16];
                #pragma unroll
                for (int k = 0; k < 16; ++k)
                    v[k] = __hip_atomic_load(hsrc + (size_t)(b0 + k) * 1024 + hoff + tid,
                                             __ATOMIC_RELAXED, __HIP_MEMORY_SCOPE_AGENT);
                #pragma unroll
                for (int k = 0; k < 16; ++k)
                    in_lds[k * 512 + tid] = v[k];
            }
            __syncthreads();
            // ---- GEMM: rows x 16 batch over this K-512 pass ----
            #pragma unroll 4
            for (int b = 0; b < 16; ++b) {
                float4 a = {0.f, 0.f, 0.f, 0.f};
                #pragma unroll
                for (int j = 0; j < 8; ++j) {
                    float4 iv = *(const float4*)&in_lds[b * 512 + s * 32 + j * 4];
                    float4 w = wv[L][p][j];
                    a.x = fmaf(w.x, iv.x, a.x); a.y = fmaf(w.y, iv.y, a.y);
                    a.z = fmaf(w.z, iv.z, a.z); a.w = fmaf(w.w, iv.w, a.w);
                }
                float vsum = (a.x + a.y) + (a.z + a.w);
                vsum += __shfl_xor(vsum, 32, 64);       // fold s-pair within wave
                if (!(s & 1)) {                          // lanes 0..31 of wave
                    float* pp = &part_lds[(b * 8 + (s >> 1)) * 32 + r];
                    if (p == 0) *pp = vsum; else *pp += vsum;
                }
            }
            __syncthreads();
        }
        // ---- stage2: sum 8 wave-pair partials -> gate value (thread = (r, b=s)) ----
        {
            float gsum = gbias[L];
            #pragma unroll
            for (int j = 0; j < 8; ++j) gsum += part_lds[(s * 8 + j) * 32 + r];
            gate_lds[r * 17 + s] = gsum;
        }
        __syncthreads();
        // ---- elementwise LSTM update: 8 features x 16 batch ----
        if (tid < 128) {
            int mi = tid & 7, b3 = tid >> 3;
            float ig = gate_lds[(0  + mi) * 17 + b3];
            float fg = gate_lds[(8  + mi) * 17 + b3];
            float og = gate_lds[(16 + mi) * 17 + b3];
            float nf = gate_lds[(24 + mi) * 17 + b3];
            float c_old = (L == 0) ? c0 : c1;
            float cn = sigm(fg) * c_old + sigm(ig) * ftanh(nf) + slotc[L];
            float hn = sigm(og) * ftanh(cn);
            if (L == 0) c0 = cn; else c1 = cn;
            int gm = m0 + mi, gb_ = b0 + b3;
            // h exchange: write-through atomic store (visible at LIC, no fence needed)
            __hip_atomic_store(hnext + (size_t)gb_ * 1024 + L * 512 + gm, hn,
                               __ATOMIC_RELAXED, __HIP_MEMORY_SCOPE_AGENT);
            if (L == 1)
                out[((size_t)gb_ * Tt + t) * Hsz + gm] = hn;
            if (t == Tt - 1) {
                out[OUT_HT + (size_t)gb_ * 1024 + L * 512 + gm] = hn;
                out[OUT_CT + (size_t)gb_ * 1024 + L * 512 + gm] = cn;
            }
        }
        // ---- group barrier: 64 blocks, slot store + wave-0 poll ----
        __syncthreads();    // drains vmcnt per wave: h stores are at LIC before slot store
        if (tid == 0)
            __hip_atomic_store(&slots[slotbase + myidx * 16], ph,
                               __ATOMIC_RELAXED, __HIP_MEMORY_SCOPE_AGENT);
        if (tid < 64) {
            int* sl = &slots[slotbase + tid * 16];
            int it = 0;
            while (__hip_atomic_load(sl, __ATOMIC_RELAXED, __HIP_MEMORY_SCOPE_AGENT) < ph) {
                __builtin_amdgcn_s_sleep(1);
                if (((++it) & 1023) == 0)
                    __builtin_amdgcn_fence(__ATOMIC_ACQUIRE, "agent"); // safety net only
            }
        }
        __syncthreads();
    };

    for (int t = 0; t < Tt; ++t) {
        const float* hprev = (t & 1) ? hbuf1 : hbuf0;
        float* hnext = (t & 1) ? hbuf0 : hbuf1;
        phase(IC<0>{}, t, hprev, hnext, 2 * t + 1);
        phase(IC<1>{}, t, hprev, hnext, 2 * t + 2);
    }
}

extern "C" void kernel_launch(void* const* d_in, const int* in_sizes, int n_in,
                              void* d_out, int out_size, void* d_ws, size_t ws_size,
                              hipStream_t stream) {
    (void)in_sizes; (void)n_in; (void)out_size; (void)ws_size;
    const float* inputs = (const float*)d_in[0];
    const float* gW = (const float*)d_in[5];
    const float* gb = (const float*)d_in[6];
    const float* sbias = (const float*)d_in[8];
    float* out = (float*)d_out;
    float* ws = (float*)d_ws;

    hipLaunchKernelGGL(sclstm_init, dim3(256), dim3(256), 0, stream, ws, out);
    hipLaunchKernelGGL(sclstm_main, dim3(NBLK), dim3(NTHR), 0, stream,
                       inputs, gW, gb, sbias, out, ws);
}

// Round 3
// 3356.706 us; speedup vs baseline: 16.6627x; 2.9097x over previous
//
#include <hip/hip_runtime.h>

// SCLSTM on MI355X — R3: bf16 MFMA, register-resident A-fragments, fragment-order LDS.
//
// Dead code (verified): s==0 forever => st==0, slot_info==tanh(sb[l]); W_ir/b_ir/W_hr/
// b_hr/sW never affect outputs. Remaining: 2-layer LSTM, B=64, T=512, H=512.
//
// R2 post-mortem: LDS-read-pipe bound (2048 ds_read_b128/CU/phase = ~10us). Fix: MFMA
// with A (weights) in VGPRs; B (inputs) staged in fragment order -> 64 b128 reads/CU.
//
// Decomposition: 256 blocks x 512 thr; block = (8 features x 16 batch), both layers.
//   4 independent sync groups of 64 blocks (group = batch tile).
//   Wave w: tau=w&1 (row tile 0..15 / 16..31), g=w>>1 (K-chunk of 256).
//   Weights: 2 layers x 8 ksteps x short8 = 64 VGPRs/lane, packed bf16 once.
// h exchange: bf16 via LIC (agent-scope atomics). Barrier: per-block slot + wave poll.

typedef unsigned short ushort;
typedef unsigned long long u64;
using bfrag = __attribute__((ext_vector_type(8))) short;
using cfrag = __attribute__((ext_vector_type(4))) float;

constexpr int NBLK = 256, NTHR = 512;
constexpr int Bsz = 64, Tt = 512, Hsz = 512;

constexpr long long OUT_HT = (long long)Bsz * Tt * Hsz;
constexpr long long OUT_CT = OUT_HT + (long long)Bsz * 2 * Hsz;
constexpr long long OUT_ST = OUT_CT + (long long)Bsz * 2 * Hsz;
constexpr int SLOTN = 4 * 64 * 16;       // ints
constexpr int HBUFN = Bsz * 2 * Hsz;     // ushorts per h buffer (65536)

template<int N> struct IC { static constexpr int value = N; };

__global__ __launch_bounds__(256) void sclstm_init(float* __restrict__ ws,
                                                   float* __restrict__ out) {
    int i = blockIdx.x * blockDim.x + threadIdx.x, st = gridDim.x * blockDim.x;
    // slots (4096 ints) + 2 bf16 h-buffers (65536 floats worth)
    for (int k = i; k < SLOTN + HBUFN / 2 * 2 / 2 * 2; k += st) ws[k] = 0.f; // SLOTN+... keep simple below
    for (int k = i; k < SLOTN + (2 * HBUFN * 2) / 4; k += st) ws[k] = 0.f;
    for (int k = i; k < Bsz * 128; k += st) out[OUT_ST + k] = 0.f;           // st == 0 always
}

__device__ __forceinline__ float sigm(float x) { return 1.f / (1.f + __expf(-x)); }
__device__ __forceinline__ float ftanh(float x) {
    float e = __expf(2.f * x);
    return 1.f - 2.f / (e + 1.f);
}
__device__ __forceinline__ ushort f2bf(float f) {
    unsigned u = __builtin_bit_cast(unsigned, f);
    u += 0x7FFFu + ((u >> 16) & 1u);
    return (ushort)(u >> 16);
}

__global__ __launch_bounds__(NTHR, 2) void sclstm_main(
    const float* __restrict__ inputs,   // (B,T,512) fp32
    const float* __restrict__ gW,       // (2, 2048, 1024) fp32
    const float* __restrict__ gb,       // (2, 2048)
    const float* __restrict__ sbias,    // (2, 512)
    float* __restrict__ out,
    float* __restrict__ ws)
{
    // B-operand panel in fragment order: 32 ksteps x 1KB (lane-slot = 8 bf16, XOR-swizzled)
    __shared__ ushort frag_lds[32 * 512];            // 32 KB
    __shared__ float part_lds[32 * 16 * 4];          // [(lrow*16+col)*4 + g]  8 KB
    __shared__ float gate_lds[32 * 17];              // [lrow][col]

    int* slots = (int*)ws;
    ushort* hbuf0 = (ushort*)(ws + SLOTN);
    ushort* hbuf1 = hbuf0 + HBUFN;

    const int tid = threadIdx.x, blk = blockIdx.x;
    const int grp = blk & 3, myidx = blk >> 2, slotbase = grp * 64 * 16;
    const int b0 = grp * 16, m0 = (blk >> 2) * 8;
    const int lane = tid & 63, wave = tid >> 6;
    const int tau = wave & 1, g = wave >> 1;         // row tile, K-group (256 K each)
    const int lm = lane & 15, quad = lane >> 4;

    // ---- one-time: pack weights into A-fragments (bf16) ----
    bfrag wv[2][8];
    {
        const int lr = tau * 16 + lm;                              // local gate row
        const int grow = (lr >> 3) * 512 + m0 + (lr & 7);          // global gate row
        #pragma unroll
        for (int l = 0; l < 2; ++l)
            #pragma unroll
            for (int j = 0; j < 8; ++j) {
                const float* src = gW + ((size_t)l * 2048 + grow) * 1024
                                      + g * 256 + j * 32 + quad * 8;
                float4 a = *(const float4*)src, b = *(const float4*)(src + 4);
                bfrag v;
                v[0] = (short)f2bf(a.x); v[1] = (short)f2bf(a.y);
                v[2] = (short)f2bf(a.z); v[3] = (short)f2bf(a.w);
                v[4] = (short)f2bf(b.x); v[5] = (short)f2bf(b.y);
                v[6] = (short)f2bf(b.z); v[7] = (short)f2bf(b.w);
                wv[l][j] = v;
            }
    }
    // reducer bias (thread t handles lrow=t>>4, col=t&15)
    float bias_r[2];
    {
        const int lrow = tid >> 4;
        const int growr = (lrow >> 3) * 512 + m0 + (lrow & 7);
        bias_r[0] = gb[growr]; bias_r[1] = gb[2048 + growr];
    }
    float slotc[2] = {0.f, 0.f};
    if (tid < 128) {
        #pragma unroll
        for (int l = 0; l < 2; ++l) slotc[l] = ftanh(sbias[l * 512 + m0 + (tid & 7)]);
    }
    float c0 = 0.f, c1 = 0.f;            // cell state (tid<128: feature tid&7, batch tid>>3)

    const int sn = tid >> 5, skc = tid & 31;   // staging: batch row, k-chunk-of-8

    auto phase = [&](auto Lc, int t, const ushort* hprevB, ushort* hnextB, int ph) {
        constexpr int L = decltype(Lc)::value;
        // ---- stage K-panel (16 batch x 1024 K) into fragment-order LDS ----
        #pragma unroll
        for (int r = 0; r < 4; ++r) {
            const int k0 = r * 256 + skc * 8;
            bfrag v;
            if (L == 0 && r < 2) {
                const float* xs = inputs + ((size_t)(b0 + sn) * Tt + t) * 512 + k0;
                float4 a = *(const float4*)xs, b = *(const float4*)(xs + 4);
                v[0] = (short)f2bf(a.x); v[1] = (short)f2bf(a.y);
                v[2] = (short)f2bf(a.z); v[3] = (short)f2bf(a.w);
                v[4] = (short)f2bf(b.x); v[5] = (short)f2bf(b.y);
                v[6] = (short)f2bf(b.z); v[7] = (short)f2bf(b.w);
            } else {
                const ushort* hs = (r < 2)
                    ? hnextB + (b0 + sn) * 1024 + k0              // cur = h0_new (L==1)
                    : hprevB + (b0 + sn) * 1024 + L * 512 + (k0 - 512);
                u64 q0 = __hip_atomic_load((const u64*)hs, __ATOMIC_RELAXED,
                                           __HIP_MEMORY_SCOPE_AGENT);
                u64 q1 = __hip_atomic_load((const u64*)(hs + 4), __ATOMIC_RELAXED,
                                           __HIP_MEMORY_SCOPE_AGENT);
                v[0] = (short)(ushort)(q0); v[1] = (short)(ushort)(q0 >> 16);
                v[2] = (short)(ushort)(q0 >> 32); v[3] = (short)(ushort)(q0 >> 48);
                v[4] = (short)(ushort)(q1); v[5] = (short)(ushort)(q1 >> 16);
                v[6] = (short)(ushort)(q1 >> 32); v[7] = (short)(ushort)(q1 >> 48);
            }
            const int ks = k0 >> 5;                 // r*8 + (skc>>2)
            const int fl = ((k0 & 31) >> 3) * 16 + sn;
            *(bfrag*)&frag_lds[ks * 512 + (fl ^ ((ks & 7) << 1)) * 8] = v;
        }
        __syncthreads();
        // ---- MFMA: 8 ksteps over this wave's K-chunk ----
        cfrag C = {0.f, 0.f, 0.f, 0.f};
        #pragma unroll
        for (int j = 0; j < 8; ++j) {
            const int ks = g * 8 + j;
            bfrag B = *(const bfrag*)&frag_lds[ks * 512 + ((lane ^ ((ks & 7) << 1)) * 8)];
            C = __builtin_amdgcn_mfma_f32_16x16x32_bf16(wv[L][j], B, C, 0, 0, 0);
        }
        // partials: C row = quad*4+reg (within tile tau), col = lm
        #pragma unroll
        for (int reg = 0; reg < 4; ++reg) {
            const int lrow = tau * 16 + quad * 4 + reg;
            part_lds[(lrow * 16 + lm) * 4 + g] = C[reg];
        }
        __syncthreads();
        // ---- reduce 4 K-group partials -> gate (thread = (lrow, col)) ----
        {
            float4 p = *(const float4*)&part_lds[tid * 4];
            gate_lds[(tid >> 4) * 17 + (tid & 15)] = p.x + p.y + p.z + p.w + bias_r[L];
        }
        __syncthreads();
        // ---- cell update: 8 features x 16 batch ----
        if (tid < 128) {
            const int mi = tid & 7, b3 = tid >> 3;
            float ig = gate_lds[(0  + mi) * 17 + b3];
            float fg = gate_lds[(8  + mi) * 17 + b3];
            float og = gate_lds[(16 + mi) * 17 + b3];
            float nf = gate_lds[(24 + mi) * 17 + b3];
            float c_old = (L == 0) ? c0 : c1;
            float cn = sigm(fg) * c_old + sigm(ig) * ftanh(nf) + slotc[L];
            float hn = sigm(og) * ftanh(cn);
            if (L == 0) c0 = cn; else c1 = cn;
            const int gm = m0 + mi, gbv = b0 + b3;
            __hip_atomic_store(hnextB + (size_t)gbv * 1024 + L * 512 + gm, f2bf(hn),
                               __ATOMIC_RELAXED, __HIP_MEMORY_SCOPE_AGENT);
            if (L == 1)
                out[((size_t)gbv * Tt + t) * Hsz + gm] = hn;
            if (t == Tt - 1) {
                out[OUT_HT + (size_t)gbv * 1024 + L * 512 + gm] = hn;
                out[OUT_CT + (size_t)gbv * 1024 + L * 512 + gm] = cn;
            }
        }
        // ---- group barrier (64 blocks): slot store + poll ----
        __syncthreads();   // emits s_waitcnt vmcnt(0): h stores at LIC before slot store
        if (tid == 0)
            __hip_atomic_store(&slots[slotbase + myidx * 16], ph,
                               __ATOMIC_RELAXED, __HIP_MEMORY_SCOPE_AGENT);
        if (tid < 64) {
            int* sl = &slots[slotbase + tid * 16];
            int it = 0;
            while (__hip_atomic_load(sl, __ATOMIC_RELAXED, __HIP_MEMORY_SCOPE_AGENT) < ph) {
                __builtin_amdgcn_s_sleep(1);
                if (((++it) & 1023) == 0)
                    __builtin_amdgcn_fence(__ATOMIC_ACQUIRE, "agent"); // safety net
            }
        }
        __syncthreads();
    };

    for (int t = 0; t < Tt; ++t) {
        const ushort* hprevB = (t & 1) ? hbuf1 : hbuf0;
        ushort* hnextB = (t & 1) ? hbuf0 : hbuf1;
        phase(IC<0>{}, t, hprevB, hnextB, 2 * t + 1);
        phase(IC<1>{}, t, hprevB, hnextB, 2 * t + 2);
    }
}

extern "C" void kernel_launch(void* const* d_in, const int* in_sizes, int n_in,
                              void* d_out, int out_size, void* d_ws, size_t ws_size,
                              hipStream_t stream) {
    (void)in_sizes; (void)n_in; (void)out_size; (void)ws_size;
    const float* inputs = (const float*)d_in[0];
    const float* gW = (const float*)d_in[5];
    const float* gb = (const float*)d_in[6];
    const float* sbias = (const float*)d_in[8];
    float* out = (float*)d_out;
    float* ws = (float*)d_ws;

    hipLaunchKernelGGL(sclstm_init, dim3(256), dim3(256), 0, stream, ws, out);
    hipLaunchKernelGGL(sclstm_main, dim3(NBLK), dim3(NTHR), 0, stream,
                       inputs, gW, gb, sbias, out, ws);
}

// Round 4
// 2553.909 us; speedup vs baseline: 21.9004x; 1.3143x over previous
//
#include <hip/hip_runtime.h>

// SCLSTM on MI355X — R4: layer-pipelined dual sets (A=layer0, B=layer1),
// conflict-free fragment staging, deferred output stores.
//
// Dead code (verified R1-R3): s==0 forever => st==0, slot_info==tanh(sb[l]);
// W_ir/b_ir/W_hr/b_hr/sW never affect outputs. Remaining: 2-layer LSTM B=64,T=512,H=512.
//
// R3 post-mortem: phase was sync-latency-bound (MfmaUtil 3.3, VALU 6.9, HBM 1.6%).
// R4: (1) split layers onto disjoint 128-block sets; L0->L1 dependency is one-way, so
// B trails A via a progress flag + h0 ring (depth 8) -> 512 serialized rounds, not 1024.
// (2) staging wave writes one full kstep row (lane-contiguous b128) -> no bank conflicts.
//
// Block = 16 features x 16 batch of ONE layer. Sync group = 32 blocks (one batch tile
// of one set). Wave: tau=wave&3 (gate), g=wave>>2 (K-half). Weights: 16 bfrags = 64 VGPR.

typedef unsigned short ushort;
typedef unsigned long long u64;
using bfrag = __attribute__((ext_vector_type(8))) short;
using cfrag = __attribute__((ext_vector_type(4))) float;

constexpr int NBLK = 256, NTHR = 512;
constexpr int Bsz = 64, Tt = 512, Hsz = 512;
constexpr int D = 8;                      // h ring depth (steps), power of 2

constexpr long long OUT_HT = (long long)Bsz * Tt * Hsz;
constexpr long long OUT_CT = OUT_HT + (long long)Bsz * 2 * Hsz;
constexpr long long OUT_ST = OUT_CT + (long long)Bsz * 2 * Hsz;

// ws layout (bytes)
constexpr int WS_SLOTS_A = 0;                               // 4 grp x 32 x 16 ints = 8KB
constexpr int WS_SLOTS_B = 8 * 1024;                        // 8KB
constexpr int WS_PROG_A  = 16 * 1024;                       // 4 x 16 ints
constexpr int WS_PROG_B  = 17 * 1024;
constexpr int WS_RING0   = 32 * 1024;                       // D x 64 x 512 ushort = 512KB
constexpr int WS_RING1   = WS_RING0 + D * Bsz * Hsz * 2;    // 512KB
constexpr int WS_TOTAL   = WS_RING1 + D * Bsz * Hsz * 2;    // ~1.06MB

__global__ __launch_bounds__(256) void sclstm_init(float* __restrict__ ws,
                                                   float* __restrict__ out) {
    int i = blockIdx.x * blockDim.x + threadIdx.x, st = gridDim.x * blockDim.x;
    for (int k = i; k < WS_TOTAL / 4; k += st) ws[k] = 0.f;   // slots, progs, rings
    for (int k = i; k < Bsz * 128; k += st) out[OUT_ST + k] = 0.f;  // st == 0 always
}

__device__ __forceinline__ float sigm(float x) { return 1.f / (1.f + __expf(-x)); }
__device__ __forceinline__ float ftanh(float x) {
    float e = __expf(2.f * x);
    return 1.f - 2.f / (e + 1.f);
}
__device__ __forceinline__ ushort f2bf(float f) {
    unsigned u = __builtin_bit_cast(unsigned, f);
    u += 0x7FFFu + ((u >> 16) & 1u);
    return (ushort)(u >> 16);
}
__device__ __forceinline__ int aload(const int* p) {
    return __hip_atomic_load(p, __ATOMIC_RELAXED, __HIP_MEMORY_SCOPE_AGENT);
}
__device__ __forceinline__ void spin_ge(const int* p, int v) {
    int it = 0;
    while (aload(p) < v) {
        __builtin_amdgcn_s_sleep(1);
        if (((++it) & 1023) == 0)
            __builtin_amdgcn_fence(__ATOMIC_ACQUIRE, "agent");  // safety net only
    }
}

__global__ __launch_bounds__(NTHR, 2) void sclstm_main(
    const float* __restrict__ inputs,   // (B,T,512) fp32
    const float* __restrict__ gW,       // (2, 2048, 1024) fp32
    const float* __restrict__ gb,       // (2, 2048)
    const float* __restrict__ sbias,    // (2, 512)
    float* __restrict__ out,
    float* __restrict__ ws)
{
    __shared__ __attribute__((aligned(16))) ushort frag_lds[32 * 512]; // 32 ks x 1KB
    __shared__ float part_lds[64 * 16 * 2];   // [(lrow*16+col)*2 + g]   8KB
    __shared__ float gate_lds[64 * 17];       // [lrow][col]             4.25KB

    char* wsb = (char*)ws;
    const int tid = threadIdx.x, blk = blockIdx.x;
    const int setB = blk & 1;                  // 0: layer0 (producer), 1: layer1
    const int grp = (blk >> 1) & 3;            // batch tile
    const int myidx = blk >> 3;                // 0..31 within group (feature tile)
    const int L = setB;
    const int b0 = grp * 16, m0 = myidx * 16;

    int* slots     = (int*)(wsb + (setB ? WS_SLOTS_B : WS_SLOTS_A)) + grp * 32 * 16;
    int* prog_self = (int*)(wsb + (setB ? WS_PROG_B : WS_PROG_A)) + grp * 16;
    int* prog_up   = (int*)(wsb + WS_PROG_A) + grp * 16;   // B waits: h0(t) ready
    int* prog_down = (int*)(wsb + WS_PROG_B) + grp * 16;   // A ring backpressure
    ushort* ring0 = (ushort*)(wsb + WS_RING0);
    ushort* ring1 = (ushort*)(wsb + WS_RING1);
    ushort* ring_rec = setB ? ring1 : ring0;   // own recurrence ring

    const int lane = tid & 63, wave = tid >> 6;
    const int tau = wave & 3, g = wave >> 2;   // gate tile, K-half (512 each)
    const int q = lane >> 4, lm = lane & 15;   // quad, col/feature-in-tile

    // ---- one-time: weights -> A-fragments (one layer, 16 ksteps) = 64 VGPRs ----
    bfrag wv[16];
    {
        const int grow = tau * 512 + m0 + lm;  // global gate row (gate tau, feature m0+lm)
        const float* wrow = gW + ((size_t)L * 2048 + grow) * 1024 + g * 512 + q * 8;
        #pragma unroll
        for (int j = 0; j < 16; ++j) {
            const float* src = wrow + j * 32;
            float4 a = *(const float4*)src, b = *(const float4*)(src + 4);
            bfrag v;
            v[0]=(short)f2bf(a.x); v[1]=(short)f2bf(a.y); v[2]=(short)f2bf(a.z); v[3]=(short)f2bf(a.w);
            v[4]=(short)f2bf(b.x); v[5]=(short)f2bf(b.y); v[6]=(short)f2bf(b.z); v[7]=(short)f2bf(b.w);
            wv[j] = v;
        }
    }
    float bias_r0, bias_r1;
    {
        const int lr0 = tid >> 4, lr1 = lr0 + 32;
        bias_r0 = gb[L * 2048 + (lr0 >> 4) * 512 + m0 + (lr0 & 15)];
        bias_r1 = gb[L * 2048 + (lr1 >> 4) * 512 + m0 + (lr1 & 15)];
    }
    float slotc = 0.f, c = 0.f;                // cell state: tid<256 = (mi=tid&15, b3=tid>>4)
    if (tid < 256) slotc = ftanh(sbias[L * 512 + m0 + (tid & 15)]);

    for (int t = 0; t < Tt; ++t) {
        const int rs_cur = t & (D - 1), rs_prev = (t - 1) & (D - 1);
        // ---- B: wait until A-group published h0(t) (single-thread spin, bcast) ----
        if (setB) {
            if (tid == 0) spin_ge(prog_up, t + 1);
            __syncthreads();
        }
        // ---- stage 32 kstep rows; wave writes full row -> lane-contiguous b128 ----
        #pragma unroll
        for (int it = 0; it < 4; ++it) {
            const int ks = it * 8 + wave;
            bfrag v;
            if (!setB && ks < 16) {            // cur = x(t), fp32 cached reads
                const float* xs = inputs + ((size_t)(b0 + lm) * Tt + t) * 512 + ks * 32 + q * 8;
                float4 a = *(const float4*)xs, b = *(const float4*)(xs + 4);
                v[0]=(short)f2bf(a.x); v[1]=(short)f2bf(a.y); v[2]=(short)f2bf(a.z); v[3]=(short)f2bf(a.w);
                v[4]=(short)f2bf(b.x); v[5]=(short)f2bf(b.y); v[6]=(short)f2bf(b.z); v[7]=(short)f2bf(b.w);
            } else {
                const ushort* hs = (ks < 16)
                    ? ring0 + (size_t)rs_cur * (Bsz * Hsz) + (b0 + lm) * 512 + ks * 32 + q * 8        // B: h0(t)
                    : ring_rec + (size_t)rs_prev * (Bsz * Hsz) + (b0 + lm) * 512 + (ks - 16) * 32 + q * 8; // own h(t-1)
                u64 q0 = __hip_atomic_load((const u64*)hs, __ATOMIC_RELAXED, __HIP_MEMORY_SCOPE_AGENT);
                u64 q1 = __hip_atomic_load((const u64*)(hs + 4), __ATOMIC_RELAXED, __HIP_MEMORY_SCOPE_AGENT);
                v[0]=(short)(ushort)(q0); v[1]=(short)(ushort)(q0 >> 16);
                v[2]=(short)(ushort)(q0 >> 32); v[3]=(short)(ushort)(q0 >> 48);
                v[4]=(short)(ushort)(q1); v[5]=(short)(ushort)(q1 >> 16);
                v[6]=(short)(ushort)(q1 >> 32); v[7]=(short)(ushort)(q1 >> 48);
            }
            *(bfrag*)&frag_lds[ks * 512 + lane * 8] = v;   // conflict-free (contiguous/wave)
        }
        __syncthreads();
        // ---- MFMA: 16 ksteps over this wave's K-half, 2 chains for latency ----
        cfrag C0 = {0.f, 0.f, 0.f, 0.f}, C1 = {0.f, 0.f, 0.f, 0.f};
        #pragma unroll
        for (int j = 0; j < 16; j += 2) {
            bfrag Bf0 = *(const bfrag*)&frag_lds[(g * 16 + j) * 512 + lane * 8];
            C0 = __builtin_amdgcn_mfma_f32_16x16x32_bf16(wv[j], Bf0, C0, 0, 0, 0);
            bfrag Bf1 = *(const bfrag*)&frag_lds[(g * 16 + j + 1) * 512 + lane * 8];
            C1 = __builtin_amdgcn_mfma_f32_16x16x32_bf16(wv[j + 1], Bf1, C1, 0, 0, 0);
        }
        #pragma unroll
        for (int reg = 0; reg < 4; ++reg) {
            const int lrow = tau * 16 + q * 4 + reg;       // C row = quad*4+reg (m89 layout)
            part_lds[(lrow * 16 + lm) * 2 + g] = C0[reg] + C1[reg];
        }
        __syncthreads();
        // ---- reduce 2 K-halves -> gates; A: ring backpressure spin (rarely taken) ----
        {
            float2 p0 = *(const float2*)&part_lds[tid * 2];
            float2 p1 = *(const float2*)&part_lds[(tid + 512) * 2];
            gate_lds[(tid >> 4) * 17 + (tid & 15)] = p0.x + p0.y + bias_r0;
            gate_lds[((tid >> 4) + 32) * 17 + (tid & 15)] = p1.x + p1.y + bias_r1;
        }
        if (!setB && t >= D && tid == 0) spin_ge(prog_down, t - D + 1);
        __syncthreads();
        // ---- cell update: 16 features x 16 batch; ring store only (out deferred) ----
        float hn = 0.f, cn = 0.f;
        if (tid < 256) {
            const int mi = tid & 15, b3 = tid >> 4;
            float ig = gate_lds[(0  + mi) * 17 + b3];
            float fg = gate_lds[(16 + mi) * 17 + b3];
            float og = gate_lds[(32 + mi) * 17 + b3];
            float nf = gate_lds[(48 + mi) * 17 + b3];
            cn = sigm(fg) * c + sigm(ig) * ftanh(nf) + slotc;
            hn = sigm(og) * ftanh(cn);
            c = cn;
            __hip_atomic_store(ring_rec + (size_t)rs_cur * (Bsz * Hsz) + (b0 + b3) * 512 + m0 + mi,
                               f2bf(hn), __ATOMIC_RELAXED, __HIP_MEMORY_SCOPE_AGENT);
        }
        // ---- group barrier (32 blocks) + publish progress ----
        __syncthreads();   // drains vmcnt per wave: ring stores at LIC before slot store
        if (tid == 0)
            __hip_atomic_store(&slots[myidx * 16], t + 1,
                               __ATOMIC_RELAXED, __HIP_MEMORY_SCOPE_AGENT);
        if (tid < 32) spin_ge(&slots[tid * 16], t + 1);
        if (myidx == 0 && tid == 0)
            __hip_atomic_store(prog_self, t + 1,
                               __ATOMIC_RELAXED, __HIP_MEMORY_SCOPE_AGENT);
        __syncthreads();
        // ---- deferred output stores (overlap next phase; drained at next barrier) ----
        if (tid < 256) {
            const int mi = tid & 15, b3 = tid >> 4;
            if (setB)
                out[((size_t)(b0 + b3) * Tt + t) * Hsz + m0 + mi] = hn;
            if (t == Tt - 1) {
                out[OUT_HT + (size_t)(b0 + b3) * 1024 + L * 512 + m0 + mi] = hn;
                out[OUT_CT + (size_t)(b0 + b3) * 1024 + L * 512 + m0 + mi] = cn;
            }
        }
    }
}

extern "C" void kernel_launch(void* const* d_in, const int* in_sizes, int n_in,
                              void* d_out, int out_size, void* d_ws, size_t ws_size,
                              hipStream_t stream) {
    (void)in_sizes; (void)n_in; (void)out_size; (void)ws_size;
    const float* inputs = (const float*)d_in[0];
    const float* gW = (const float*)d_in[5];
    const float* gb = (const float*)d_in[6];
    const float* sbias = (const float*)d_in[8];
    float* out = (float*)d_out;
    float* ws = (float*)d_ws;

    hipLaunchKernelGGL(sclstm_init, dim3(256), dim3(256), 0, stream, ws, out);
    hipLaunchKernelGGL(sclstm_main, dim3(NBLK), dim3(NTHR), 0, stream,
                       inputs, gW, gb, sbias, out, ws);
}